// Round 14
// baseline (737.450 us; speedup 1.0000x reference)
//
#include <hip/hip_runtime.h>

namespace {

constexpr int kB = 64;
constexpr int kL = 4096;
constexpr float kLrW = 1.0f / 64.0f;
constexpr float kLrF = 1.0f / 128.0f;
constexpr float kGradMax = 30.0f;
constexpr float kEps = 1e-9f;
constexpr int kPF = 8;
constexpr int kNC = kL / kPF;

#define DPP_ADD_F32(v, ctrl)                                                   \
    v += __int_as_float(__builtin_amdgcn_update_dpp(                           \
        0, __float_as_int(v), (ctrl), 0xF, 0xF, true))

__device__ __forceinline__ float rl(float v, int l) {
    return __int_as_float(__builtin_amdgcn_readlane(__float_as_int(v), l));
}
__device__ __forceinline__ float frcp(float x) { return __builtin_amdgcn_rcpf(x); }
__device__ __forceinline__ float frsq(float x) { return __builtin_amdgcn_rsqf(x); }

// ---------------- packed-f32 complex primitives (VOP3P, r13-proven) --------
__device__ __forceinline__ void cfma(float2& a, const float2 s, const float2 u) {
    asm("v_pk_fma_f32 %0, %1, %2, %0 op_sel:[1,1,0] op_sel_hi:[1,0,1] neg_lo:[0,1,0]\n\t"
        "v_pk_fma_f32 %0, %1, %2, %0 op_sel:[0,0,0] op_sel_hi:[0,1,1]"
        : "+v"(a) : "v"(s), "v"(u));
}
__device__ __forceinline__ void cfma_conj(float2& a, const float2 s, const float2 u) {
    asm("v_pk_fma_f32 %0, %1, %2, %0 op_sel:[1,1,0] op_sel_hi:[1,0,1]\n\t"
        "v_pk_fma_f32 %0, %1, %2, %0 op_sel:[0,0,0] op_sel_hi:[0,1,1] neg_hi:[0,1,0]"
        : "+v"(a) : "v"(s), "v"(u));
}
__device__ __forceinline__ float2 cmul(const float2 s, const float2 u) {
    float2 r;
    asm("v_pk_mul_f32 %0, %1, %2 op_sel:[1,1] op_sel_hi:[1,0] neg_lo:[0,1]\n\t"
        "v_pk_fma_f32 %0, %1, %2, %0 op_sel:[0,0,0] op_sel_hi:[0,1,1]"
        : "=&v"(r) : "v"(s), "v"(u));
    return r;
}
__device__ __forceinline__ float2 cmul_conj(const float2 s, const float2 u) {
    float2 r;
    asm("v_pk_mul_f32 %0, %1, %2 op_sel:[1,1] op_sel_hi:[1,0]\n\t"
        "v_pk_fma_f32 %0, %1, %2, %0 op_sel:[0,0,0] op_sel_hi:[0,1,1] neg_hi:[0,1,0]"
        : "=&v"(r) : "v"(s), "v"(u));
    return r;
}
__device__ __forceinline__ float2 pk_fnma(const float2 s, const float2 u, const float2 c) {
    float2 r;
    asm("v_pk_fma_f32 %0, %1, %2, %3 neg_lo:[1,0,0] neg_hi:[1,0,0]"
        : "=v"(r) : "v"(s), "v"(u), "v"(c));
    return r;
}
__device__ __forceinline__ float2 pk_sub(const float2 a, const float2 b) {
    float2 r;
    asm("v_pk_add_f32 %0, %1, %2 neg_lo:[0,1] neg_hi:[0,1]" : "=v"(r) : "v"(a), "v"(b));
    return r;
}
__device__ __forceinline__ float2 pk_mul(const float2 a, const float2 b) {
    float2 r;
    asm("v_pk_mul_f32 %0, %1, %2" : "=v"(r) : "v"(a), "v"(b));
    return r;
}

typedef unsigned u32x2v __attribute__((ext_vector_type(2)));
// Row-pair sum (r10-proven): after rowsum16, gives the 32-group sum uniform
// in every lane of that 32-half. No readlane, no SALU round-trip.
__device__ __forceinline__ float pairsum16(float v) {
    u32x2v r = __builtin_amdgcn_permlane16_swap(__float_as_uint(v),
                                                __float_as_uint(v), false, false);
    return __uint_as_float(r[0]) + __uint_as_float(r[1]);
}
// Half-pair sum: v(lane) + v(lane^32), uniform across the wave.
__device__ __forceinline__ float pairsum32(float v) {
    u32x2v r = __builtin_amdgcn_permlane32_swap(__float_as_uint(v),
                                                __float_as_uint(v), false, false);
    return __uint_as_float(r[0]) + __uint_as_float(r[1]);
}
// Circular all-reduce within each row of 16 (r10-proven).
__device__ __forceinline__ float rowsum16(float v) {
    DPP_ADD_F32(v, 0x121); DPP_ADD_F32(v, 0x122);
    DPP_ADD_F32(v, 0x124); DPP_ADD_F32(v, 0x128);
    return v;
}

typedef const __attribute__((address_space(1))) float gfloat;

// ---------- pre-kernel (r10/r13-proven): meta[b,t][8]={su,su,d0r,d0i,d1r,d1i,0,0}
__global__ __launch_bounds__(256, 1) void pre_kernel(
    const float* __restrict__ u_r, const float* __restrict__ u_i,
    const float* __restrict__ x_r, const float* __restrict__ x_i,
    float* __restrict__ meta)
{
    const int lane = threadIdx.x & 63;
    const int idx = blockIdx.x * 4 + (threadIdx.x >> 6);   // flat b*L + t
    const float a = u_r[(size_t)idx * 64 + lane];
    const float c = u_i[(size_t)idx * 64 + lane];
    float e = fmaf(a, a, c * c);
    e = rowsum16(e);
    e = pairsum16(e);
    e = pairsum32(e);
    if (lane == 0) {
        const float su = kLrW * frcp(e + kEps);
        const float2 xr = *(const float2*)(x_r + (size_t)idx * 2);
        const float2 xi = *(const float2*)(x_i + (size_t)idx * 2);
        float4* m = (float4*)(meta + (size_t)idx * 8);
        m[0] = make_float4(su, su, xr.x, xi.x);
        m[1] = make_float4(xr.y, xi.y, 0.0f, 0.0f);
    }
}

// ---------- main scan kernel: r13 skeleton, readlane-free reduce ------------
__global__ __launch_bounds__(64, 1) void adf_kernel(
    const float* __restrict__ u_r, const float* __restrict__ u_i,
    const float* __restrict__ w0r_g, const float* __restrict__ w0i_g,
    const float* __restrict__ f0r_g, const float* __restrict__ f0i_g,
    const float* __restrict__ meta, float* __restrict__ out)
{
    const int b = blockIdx.x;
    const int lane = threadIdx.x;
    const int half = lane >> 5;
    const int tap  = lane & 31;

    const int wbase = b * 128 + half * 64 + tap;
    float2 wA = make_float2(w0r_g[wbase],      w0i_g[wbase]);
    float2 wB = make_float2(w0r_g[wbase + 32], w0i_g[wbase + 32]);

    float2 f2 = make_float2(f0r_g[b * 2 + half], f0i_g[b * 2 + half]);
    float2 psi2;
    {
        const float iv = frsq(fmaf(f2.x, f2.x, f2.y * f2.y));
        psi2 = make_float2(f2.x * iv, -f2.y * iv);
    }

    const float2* __restrict__ ur2 = (const float2*)u_r + (size_t)b * kL * 32;
    const float2* __restrict__ ui2 = (const float2*)u_i + (size_t)b * kL * 32;
    const float* __restrict__ mp = meta + (size_t)b * kL * 8;
    float2* __restrict__ ob2 = (float2*)out + (size_t)b * kL * 2;

    float2 Au[kPF], Aq[kPF], Asu[kPF], Ad[kPF];
    float2 Bu[kPF], Bq[kPF], Bsu[kPF], Bd[kPF];
    float2 kO[kPF];
    float2 sdp2 = make_float2(0.f, 0.f);

    auto loadChunk = [&](float2 (&u)[kPF], float2 (&q)[kPF],
                         float2 (&su)[kPF], float2 (&d)[kPF], int chunk) {
#pragma unroll
        for (int s = 0; s < kPF; ++s) {
            int t = chunk * kPF + s;
            t = t < kL ? t : kL - 1;
            u[s]  = ur2[(size_t)t * 32 + tap];
            q[s]  = ui2[(size_t)t * 32 + tap];
            su[s] = *(const float2*)(mp + (size_t)t * 8);                  // (su,su)
            d[s]  = *(const float2*)(mp + (size_t)t * 8 + 2 + 2 * half);   // (dr,di)
        }
        __builtin_amdgcn_sched_barrier(0);   // keep prefetch ahead of compute (r7)
    };

    auto body = [&](int s, float2 (&u)[kPF], float2 (&q)[kPF],
                    float2 (&su)[kPF], float2 (&d)[kPF], bool first) {
        // repack complex operands (re,im) from split arrays
        const float2 cA = make_float2(u[s].x, q[s].x);
        const float2 cB = make_float2(u[s].y, q[s].y);
        if (first) {   // chunk-entry sdp from carried psi
            sdp2 = pk_mul(su[0], cmul(d[0], psi2));
        }
        // dot partials (packed) + ror-reduce + permlane pair-sum:
        // v lands UNIFORM per 32-half directly in VGPRs (no readlane/cndmask)
        float2 p = cmul(wA, cA);
        cfma(p, wB, cB);
        float pr = p.x, pi = p.y;
        DPP_ADD_F32(pr, 0x121); DPP_ADD_F32(pi, 0x121);
        DPP_ADD_F32(pr, 0x122); DPP_ADD_F32(pi, 0x122);
        DPP_ADD_F32(pr, 0x124); DPP_ADD_F32(pi, 0x124);
        DPP_ADD_F32(pr, 0x128); DPP_ADD_F32(pi, 0x128);
        pr = pairsum16(pr);
        pi = pairsum16(pi);
        const float2 v2 = make_float2(pr, pi);

        // ven = |v0|^2 + |v1|^2 via cross-half pair-sum (uniform), rcp early
        const float mv2 = fmaf(pr, pr, pi * pi);
        const float ven = pairsum32(mv2) + kEps;
        const float nv = frcp(ven);

        // tau = sdp - su*v ; w += tau*conj(u)
        const float2 tau = pk_fnma(su[s], v2, sdp2);
        cfma_conj(wA, tau, cA);
        cfma_conj(wB, tau, cB);

        // f-path
        const float2 k2 = cmul(v2, f2);            // k = v*f (pre-update f)
        kO[s] = k2;
        const float2 ef = pk_sub(d[s], k2);        // e_f = d - k
        const float2 H = cmul_conj(ef, v2);        // ef*conj(v)
        const float MH = fmaf(H.x, H.x, H.y * H.y);
        const float sc = fminf(nv, kGradMax * frsq(MH));   // norm+clip folded
        const float scl = kLrF * sc;
        f2.x = fmaf(scl, H.x, f2.x);               // f -= lrF*gf
        f2.y = fmaf(scl, H.y, f2.y);
        const float iff = frsq(fmaf(f2.x, f2.x, f2.y * f2.y));
        psi2 = make_float2(f2.x * iff, -f2.y * iff);
        if (s + 1 < kPF) {
            sdp2 = pk_mul(su[s + 1], cmul(d[s + 1], psi2));
        }
    };

    auto processChunk = [&](int tbase, float2 (&u)[kPF], float2 (&q)[kPF],
                            float2 (&su)[kPF], float2 (&d)[kPF]) {
#pragma unroll
        for (int s = 0; s < kPF; ++s)
            body(s, u, q, su, d, s == 0);
        if (tap == 0) {
#pragma unroll
            for (int s = 0; s < kPF; ++s)
                ob2[(size_t)(tbase + s) * 2 + half] = kO[s];
        }
    };

    loadChunk(Au, Aq, Asu, Ad, 0);
    loadChunk(Bu, Bq, Bsu, Bd, 1);

    for (int c = 0; c < kNC; c += 2) {
        processChunk(c * kPF, Au, Aq, Asu, Ad);
        loadChunk(Au, Aq, Asu, Ad, (c + 2 < kNC) ? c + 2 : kNC - 1);
        processChunk((c + 1) * kPF, Bu, Bq, Bsu, Bd);
        loadChunk(Bu, Bq, Bsu, Bd, (c + 3 < kNC) ? c + 3 : kNC - 1);
    }
}

// ---------- fallback (r7, 838 us, proven) if ws too small -------------------
__global__ __launch_bounds__(64, 1) void adf_fb(
    const float* __restrict__ u_r, const float* __restrict__ u_i,
    const float* __restrict__ x_r, const float* __restrict__ x_i,
    const float* __restrict__ w0r_g, const float* __restrict__ w0i_g,
    const float* __restrict__ f0r_g, const float* __restrict__ f0i_g,
    float* __restrict__ out)
{
    const int b = blockIdx.x;
    const int lane = threadIdx.x;
    const int half = lane >> 5;
    const int tap  = lane & 31;
    const bool lo  = (half == 0);

    const int wbase = b * 128 + half * 64 + tap;
    float wAr = w0r_g[wbase],      wAi = w0i_g[wbase];
    float wBr = w0r_g[wbase + 32], wBi = w0i_g[wbase + 32];

    float fr = f0r_g[b * 2 + half];
    float fi = f0i_g[b * 2 + half];
    const float invf0 = frsq(fmaf(fr, fr, fi * fi));
    float psr = fr * invf0, psm = -fi * invf0;

    const float2* __restrict__ ur2 = (const float2*)u_r + (size_t)b * kL * 32;
    const float2* __restrict__ ui2 = (const float2*)u_i + (size_t)b * kL * 32;
    const float2* __restrict__ xr2 = (const float2*)x_r + (size_t)b * kL;
    const float2* __restrict__ xi2 = (const float2*)x_i + (size_t)b * kL;
    float2* __restrict__ ob2 = (float2*)out + (size_t)b * kL * 2;

    float2 Au[kPF], Aq[kPF], AxR[kPF], AxI[kPF];
    float2 Bu[kPF], Bq[kPF], BxR[kPF], BxI[kPF];
    float suA[kPF], suB[kPF];
    float kR[kPF], kI[kPF];
    float sdpr = 0.0f, sdpi = 0.0f;

    auto loadChunk = [&](float2 (&u)[kPF], float2 (&q)[kPF],
                         float2 (&xR)[kPF], float2 (&xI)[kPF], int chunk) {
#pragma unroll
        for (int s = 0; s < kPF; ++s) {
            int t = chunk * kPF + s;
            t = t < kL ? t : kL - 1;
            u[s]  = ur2[(size_t)t * 32 + tap];
            q[s]  = ui2[(size_t)t * 32 + tap];
            xR[s] = xr2[t];
            xI[s] = xi2[t];
        }
        __builtin_amdgcn_sched_barrier(0);
    };

    auto calcSu = [&](float2 (&u)[kPF], float2 (&q)[kPF], float (&su)[kPF]) {
        float e[kPF];
#pragma unroll
        for (int s = 0; s < kPF; ++s) {
            float t0 = u[s].x * u[s].x;
            t0 = fmaf(u[s].y, u[s].y, t0);
            t0 = fmaf(q[s].x, q[s].x, t0);
            t0 = fmaf(q[s].y, q[s].y, t0);
            e[s] = t0;
        }
#pragma unroll
        for (int s = 0; s < kPF; ++s) { DPP_ADD_F32(e[s], 0x111); }
#pragma unroll
        for (int s = 0; s < kPF; ++s) { DPP_ADD_F32(e[s], 0x112); }
#pragma unroll
        for (int s = 0; s < kPF; ++s) { DPP_ADD_F32(e[s], 0x114); }
#pragma unroll
        for (int s = 0; s < kPF; ++s) { DPP_ADD_F32(e[s], 0x118); }
#pragma unroll
        for (int s = 0; s < kPF; ++s) { DPP_ADD_F32(e[s], 0x142); }
#pragma unroll
        for (int s = 0; s < kPF; ++s) su[s] = kLrW * frcp(rl(e[s], 31) + kEps);
    };

    auto body = [&](int s, float2 (&u)[kPF], float2 (&q)[kPF],
                    float2 (&xR)[kPF], float2 (&xI)[kPF], float (&su)[kPF],
                    bool first) {
        const float2 uc = u[s], qc = q[s];
        if (first) {
            const float dr0 = lo ? xR[0].x : xR[0].y;
            const float di0 = lo ? xI[0].x : xI[0].y;
            sdpr = su[0] * fmaf(dr0, psr, -di0 * psm);
            sdpi = su[0] * fmaf(dr0, psm,  di0 * psr);
        }
        float pr = wAr * uc.x;
        pr = fmaf(-wAi, qc.x, pr); pr = fmaf(wBr, uc.y, pr); pr = fmaf(-wBi, qc.y, pr);
        float pi = wAr * qc.x;
        pi = fmaf(wAi, uc.x, pi); pi = fmaf(wBr, qc.y, pi); pi = fmaf(wBi, uc.y, pi);
        DPP_ADD_F32(pr, 0x111); DPP_ADD_F32(pi, 0x111);
        DPP_ADD_F32(pr, 0x112); DPP_ADD_F32(pi, 0x112);
        DPP_ADD_F32(pr, 0x114); DPP_ADD_F32(pi, 0x114);
        DPP_ADD_F32(pr, 0x118); DPP_ADD_F32(pi, 0x118);
        DPP_ADD_F32(pr, 0x142); DPP_ADD_F32(pi, 0x142);
        const float v0r = rl(pr, 31), v1r = rl(pr, 63);
        const float v0i = rl(pi, 31), v1i = rl(pi, 63);
        const float vr = lo ? v0r : v1r;
        const float vi = lo ? v0i : v1i;

        const float sun = su[s];
        const float tr = fmaf(-sun, vr, sdpr);
        const float ti = fmaf(-sun, vi, sdpi);
        wAr = fmaf(tr, uc.x, fmaf(ti, qc.x, wAr));
        wAi = fmaf(ti, uc.x, fmaf(-tr, qc.x, wAi));
        wBr = fmaf(tr, uc.y, fmaf(ti, qc.y, wBr));
        wBi = fmaf(ti, uc.y, fmaf(-tr, qc.y, wBi));

        const float dr = lo ? xR[s].x : xR[s].y;
        const float di = lo ? xI[s].x : xI[s].y;
        const float kr = fmaf(vr, fr, -vi * fi);
        const float ki = fmaf(vr, fi,  vi * fr);
        kR[s] = kr; kI[s] = ki;
        const float efr = dr - kr, efi = di - ki;
        float ven = v0r * v0r;
        ven = fmaf(v0i, v0i, ven);
        ven = fmaf(v1r, v1r, ven);
        ven = fmaf(v1i, v1i, ven);
        const float nv = frcp(ven + kEps);
        float hr = efr * vr; hr = fmaf(efi, vi, hr);
        float hi = efi * vr; hi = fmaf(-efr, vi, hi);
        hr *= nv; hi *= nv;
        float mg = hr * hr; mg = fmaf(hi, hi, mg);
        const float sc = fminf(1.0f, kGradMax * frsq(mg));
        const float scl = kLrF * sc;
        fr = fmaf(scl, hr, fr);
        fi = fmaf(scl, hi, fi);
        const float invf = frsq(fmaf(fr, fr, fi * fi));
        psr = fr * invf; psm = -fi * invf;
        if (s + 1 < kPF) {
            const float dnr = lo ? xR[s + 1].x : xR[s + 1].y;
            const float dni = lo ? xI[s + 1].x : xI[s + 1].y;
            sdpr = su[s + 1] * fmaf(dnr, psr, -dni * psm);
            sdpi = su[s + 1] * fmaf(dnr, psm,  dni * psr);
        }
    };

    auto processChunk = [&](int tbase, float2 (&u)[kPF], float2 (&q)[kPF],
                            float2 (&xR)[kPF], float2 (&xI)[kPF], float (&su)[kPF]) {
#pragma unroll
        for (int s = 0; s < kPF; ++s)
            body(s, u, q, xR, xI, su, s == 0);
        if (tap == 0) {
#pragma unroll
            for (int s = 0; s < kPF; ++s)
                ob2[(size_t)(tbase + s) * 2 + half] = make_float2(kR[s], kI[s]);
        }
    };

    loadChunk(Au, Aq, AxR, AxI, 0);
    loadChunk(Bu, Bq, BxR, BxI, 1);
    calcSu(Au, Aq, suA);

    for (int c = 0; c < kNC; c += 2) {
        processChunk(c * kPF, Au, Aq, AxR, AxI, suA);
        loadChunk(Au, Aq, AxR, AxI, (c + 2 < kNC) ? c + 2 : kNC - 1);
        calcSu(Bu, Bq, suB);
        processChunk((c + 1) * kPF, Bu, Bq, BxR, BxI, suB);
        loadChunk(Bu, Bq, BxR, BxI, (c + 3 < kNC) ? c + 3 : kNC - 1);
        calcSu(Au, Aq, suA);
    }
}

} // namespace

extern "C" void kernel_launch(void* const* d_in, const int* in_sizes, int n_in,
                              void* d_out, int out_size, void* d_ws, size_t ws_size,
                              hipStream_t stream) {
    const float* u_r  = (const float*)d_in[0];
    const float* u_i  = (const float*)d_in[1];
    const float* x_r  = (const float*)d_in[2];
    const float* x_i  = (const float*)d_in[3];
    const float* w0_r = (const float*)d_in[4];
    const float* w0_i = (const float*)d_in[5];
    const float* f0_r = (const float*)d_in[6];
    const float* f0_i = (const float*)d_in[7];
    float* out = (float*)d_out;

    const size_t need = (size_t)kB * kL * 8 * sizeof(float);   // 8 MB meta
    if (ws_size >= need) {
        float* meta = (float*)d_ws;
        pre_kernel<<<dim3(kB * kL / 4), dim3(256), 0, stream>>>(u_r, u_i, x_r, x_i, meta);
        adf_kernel<<<dim3(kB), dim3(64), 0, stream>>>(
            u_r, u_i, w0_r, w0_i, f0_r, f0_i, meta, out);
    } else {
        adf_fb<<<dim3(kB), dim3(64), 0, stream>>>(
            u_r, u_i, x_r, x_i, w0_r, w0_i, f0_r, f0_i, out);
    }
}

// Round 16
// 720.139 us; speedup vs baseline: 1.0240x; 1.0240x over previous
//
#include <hip/hip_runtime.h>

namespace {

constexpr int kB = 64;
constexpr int kL = 4096;
constexpr float kLrW = 1.0f / 64.0f;
constexpr float kLrF = 1.0f / 128.0f;
constexpr float kGradMax = 30.0f;
constexpr float kEps = 1e-9f;
constexpr int kPF = 8;
constexpr int kNC = kL / kPF;

#define DPP_ADD_F32(v, ctrl)                                                   \
    v += __int_as_float(__builtin_amdgcn_update_dpp(                           \
        0, __float_as_int(v), (ctrl), 0xF, 0xF, true))

__device__ __forceinline__ float rl(float v, int l) {
    return __int_as_float(__builtin_amdgcn_readlane(__float_as_int(v), l));
}
__device__ __forceinline__ float frcp(float x) { return __builtin_amdgcn_rcpf(x); }
__device__ __forceinline__ float frsq(float x) { return __builtin_amdgcn_rsqf(x); }

// ---------------- packed-f32 complex primitives (VOP3P, r13-proven) --------
// NOTE: every v_pk_* source must be a 64-bit VGPR PAIR (r15 failed passing a
// lone scalar VGPR). Scalars are duplicated into a float2 first.
__device__ __forceinline__ void cfma(float2& a, const float2 s, const float2 u) {
    asm("v_pk_fma_f32 %0, %1, %2, %0 op_sel:[1,1,0] op_sel_hi:[1,0,1] neg_lo:[0,1,0]\n\t"
        "v_pk_fma_f32 %0, %1, %2, %0 op_sel:[0,0,0] op_sel_hi:[0,1,1]"
        : "+v"(a) : "v"(s), "v"(u));
}
__device__ __forceinline__ void cfma_conj(float2& a, const float2 s, const float2 u) {
    asm("v_pk_fma_f32 %0, %1, %2, %0 op_sel:[1,1,0] op_sel_hi:[1,0,1]\n\t"
        "v_pk_fma_f32 %0, %1, %2, %0 op_sel:[0,0,0] op_sel_hi:[0,1,1] neg_hi:[0,1,0]"
        : "+v"(a) : "v"(s), "v"(u));
}
__device__ __forceinline__ float2 cmul(const float2 s, const float2 u) {
    float2 r;
    asm("v_pk_mul_f32 %0, %1, %2 op_sel:[1,1] op_sel_hi:[1,0] neg_lo:[0,1]\n\t"
        "v_pk_fma_f32 %0, %1, %2, %0 op_sel:[0,0,0] op_sel_hi:[0,1,1]"
        : "=&v"(r) : "v"(s), "v"(u));
    return r;
}
__device__ __forceinline__ float2 cmul_conj(const float2 s, const float2 u) {
    float2 r;
    asm("v_pk_mul_f32 %0, %1, %2 op_sel:[1,1] op_sel_hi:[1,0]\n\t"
        "v_pk_fma_f32 %0, %1, %2, %0 op_sel:[0,0,0] op_sel_hi:[0,1,1] neg_hi:[0,1,0]"
        : "=&v"(r) : "v"(s), "v"(u));
    return r;
}
__device__ __forceinline__ float2 pk_fnma(const float2 s, const float2 u, const float2 c) {
    float2 r;
    asm("v_pk_fma_f32 %0, %1, %2, %3 neg_lo:[1,0,0] neg_hi:[1,0,0]"
        : "=v"(r) : "v"(s), "v"(u), "v"(c));
    return r;
}
__device__ __forceinline__ float2 pk_sub(const float2 a, const float2 b) {
    float2 r;
    asm("v_pk_add_f32 %0, %1, %2 neg_lo:[0,1] neg_hi:[0,1]" : "=v"(r) : "v"(a), "v"(b));
    return r;
}
__device__ __forceinline__ float2 pk_mul(const float2 a, const float2 b) {
    float2 r;
    asm("v_pk_mul_f32 %0, %1, %2" : "=v"(r) : "v"(a), "v"(b));
    return r;
}

typedef unsigned u32x2v __attribute__((ext_vector_type(2)));
__device__ __forceinline__ float pairsum16(float v) {
    u32x2v r = __builtin_amdgcn_permlane16_swap(__float_as_uint(v),
                                                __float_as_uint(v), false, false);
    return __uint_as_float(r[0]) + __uint_as_float(r[1]);
}
__device__ __forceinline__ float pairsum32(float v) {
    u32x2v r = __builtin_amdgcn_permlane32_swap(__float_as_uint(v),
                                                __float_as_uint(v), false, false);
    return __uint_as_float(r[0]) + __uint_as_float(r[1]);
}
__device__ __forceinline__ float rowsum16(float v) {
    DPP_ADD_F32(v, 0x121); DPP_ADD_F32(v, 0x122);
    DPP_ADD_F32(v, 0x124); DPP_ADD_F32(v, 0x128);
    return v;
}

// ---------- pre-kernel (r10/r13-proven): meta[b,t][8]={su,su,d0r,d0i,d1r,d1i,0,0}
__global__ __launch_bounds__(256, 1) void pre_kernel(
    const float* __restrict__ u_r, const float* __restrict__ u_i,
    const float* __restrict__ x_r, const float* __restrict__ x_i,
    float* __restrict__ meta)
{
    const int lane = threadIdx.x & 63;
    const int idx = blockIdx.x * 4 + (threadIdx.x >> 6);   // flat b*L + t
    const float a = u_r[(size_t)idx * 64 + lane];
    const float c = u_i[(size_t)idx * 64 + lane];
    float e = fmaf(a, a, c * c);
    e = rowsum16(e);
    e = pairsum16(e);
    e = pairsum32(e);
    if (lane == 0) {
        const float su = kLrW * frcp(e + kEps);
        const float2 xr = *(const float2*)(x_r + (size_t)idx * 2);
        const float2 xi = *(const float2*)(x_i + (size_t)idx * 2);
        float4* m = (float4*)(meta + (size_t)idx * 8);
        m[0] = make_float4(su, su, xr.x, xi.x);
        m[1] = make_float4(xr.y, xi.y, 0.0f, 0.0f);
    }
}

// ---------- main scan kernel: r13 skeleton + psi-free sdp -------------------
__global__ __launch_bounds__(64, 1) void adf_kernel(
    const float* __restrict__ u_r, const float* __restrict__ u_i,
    const float* __restrict__ w0r_g, const float* __restrict__ w0i_g,
    const float* __restrict__ f0r_g, const float* __restrict__ f0i_g,
    const float* __restrict__ meta, float* __restrict__ out)
{
    const int b = blockIdx.x;
    const int lane = threadIdx.x;
    const int half = lane >> 5;
    const int tap  = lane & 31;

    const int wbase = b * 128 + half * 64 + tap;
    float2 wA = make_float2(w0r_g[wbase],      w0i_g[wbase]);
    float2 wB = make_float2(w0r_g[wbase + 32], w0i_g[wbase + 32]);

    float2 f2 = make_float2(f0r_g[b * 2 + half], f0i_g[b * 2 + half]);
    float invf = frsq(fmaf(f2.x, f2.x, f2.y * f2.y));   // carried: 1/|f|

    const float2* __restrict__ ur2 = (const float2*)u_r + (size_t)b * kL * 32;
    const float2* __restrict__ ui2 = (const float2*)u_i + (size_t)b * kL * 32;
    const float* __restrict__ mp = meta + (size_t)b * kL * 8;
    float2* __restrict__ ob2 = (float2*)out + (size_t)b * kL * 2;

    float2 Au[kPF], Aq[kPF], Asu[kPF], Ad[kPF];
    float2 Bu[kPF], Bq[kPF], Bsu[kPF], Bd[kPF];
    float2 kO[kPF];
    float2 sdp2 = make_float2(0.f, 0.f);

    auto loadChunk = [&](float2 (&u)[kPF], float2 (&q)[kPF],
                         float2 (&su)[kPF], float2 (&d)[kPF], int chunk) {
#pragma unroll
        for (int s = 0; s < kPF; ++s) {
            int t = chunk * kPF + s;
            t = t < kL ? t : kL - 1;
            u[s]  = ur2[(size_t)t * 32 + tap];
            q[s]  = ui2[(size_t)t * 32 + tap];
            su[s] = *(const float2*)(mp + (size_t)t * 8);                  // (su,su)
            d[s]  = *(const float2*)(mp + (size_t)t * 8 + 2 + 2 * half);   // (dr,di)
        }
        __builtin_amdgcn_sched_barrier(0);   // keep prefetch ahead of compute (r7)
    };

    // sdp = (su*invf) * (d*conj(f)) -- psi-free: cmul_conj(d,f) runs parallel
    // to the frsq chain that produced invf; su*invf is scalar then duplicated.
    auto mk_sdp = [&](const float2 su, const float2 d) {
        const float2 P = cmul_conj(d, f2);
        const float g = su.x * invf;
        return pk_mul(make_float2(g, g), P);
    };

    auto body = [&](int s, float2 (&u)[kPF], float2 (&q)[kPF],
                    float2 (&su)[kPF], float2 (&d)[kPF], bool first) {
        // repack complex operands (re,im) from split arrays
        const float2 cA = make_float2(u[s].x, q[s].x);
        const float2 cB = make_float2(u[s].y, q[s].y);
        if (first) {   // chunk-entry sdp from carried f/invf
            sdp2 = mk_sdp(su[0], d[0]);
        }
        // dot partials (packed) + 5-level DPP reduce + readlane broadcast (r13)
        float2 p = cmul(wA, cA);
        cfma(p, wB, cB);
        float pr = p.x, pi = p.y;
        DPP_ADD_F32(pr, 0x111); DPP_ADD_F32(pi, 0x111);
        DPP_ADD_F32(pr, 0x112); DPP_ADD_F32(pi, 0x112);
        DPP_ADD_F32(pr, 0x114); DPP_ADD_F32(pi, 0x114);
        DPP_ADD_F32(pr, 0x118); DPP_ADD_F32(pi, 0x118);
        DPP_ADD_F32(pr, 0x142); DPP_ADD_F32(pi, 0x142);
        const float v0r = rl(pr, 31), v1r = rl(pr, 63);
        const float v0i = rl(pi, 31), v1i = rl(pi, 63);
        const float2 v2 = make_float2(half ? v1r : v0r, half ? v1i : v0i);

        // tau = sdp - su*v ; w += tau*conj(u)
        const float2 tau = pk_fnma(su[s], v2, sdp2);
        cfma_conj(wA, tau, cA);
        cfma_conj(wB, tau, cB);

        // f-path
        const float2 k2 = cmul(v2, f2);            // k = v*f (pre-update f)
        kO[s] = k2;
        const float2 ef = pk_sub(d[s], k2);        // e_f = d - k
        float ven = v0r * v0r;
        ven = fmaf(v0i, v0i, ven);
        ven = fmaf(v1r, v1r, ven);
        ven = fmaf(v1i, v1i, ven);
        const float nv = frcp(ven + kEps);
        const float2 H = cmul_conj(ef, v2);        // ef*conj(v)
        const float MH = fmaf(H.x, H.x, H.y * H.y);
        const float sc = fminf(nv, kGradMax * frsq(MH));   // norm+clip folded
        const float scl = kLrF * sc;
        f2.x = fmaf(scl, H.x, f2.x);               // f -= lrF*gf
        f2.y = fmaf(scl, H.y, f2.y);
        invf = frsq(fmaf(f2.x, f2.x, f2.y * f2.y));
        if (s + 1 < kPF) {
            sdp2 = mk_sdp(su[s + 1], d[s + 1]);
        }
    };

    auto processChunk = [&](int tbase, float2 (&u)[kPF], float2 (&q)[kPF],
                            float2 (&su)[kPF], float2 (&d)[kPF]) {
#pragma unroll
        for (int s = 0; s < kPF; ++s)
            body(s, u, q, su, d, s == 0);
        if (tap == 0) {
#pragma unroll
            for (int s = 0; s < kPF; ++s)
                ob2[(size_t)(tbase + s) * 2 + half] = kO[s];
        }
    };

    loadChunk(Au, Aq, Asu, Ad, 0);
    loadChunk(Bu, Bq, Bsu, Bd, 1);

    for (int c = 0; c < kNC; c += 2) {
        processChunk(c * kPF, Au, Aq, Asu, Ad);
        loadChunk(Au, Aq, Asu, Ad, (c + 2 < kNC) ? c + 2 : kNC - 1);
        processChunk((c + 1) * kPF, Bu, Bq, Bsu, Bd);
        loadChunk(Bu, Bq, Bsu, Bd, (c + 3 < kNC) ? c + 3 : kNC - 1);
    }
}

// ---------- fallback (r7, 838 us, proven) if ws too small -------------------
__global__ __launch_bounds__(64, 1) void adf_fb(
    const float* __restrict__ u_r, const float* __restrict__ u_i,
    const float* __restrict__ x_r, const float* __restrict__ x_i,
    const float* __restrict__ w0r_g, const float* __restrict__ w0i_g,
    const float* __restrict__ f0r_g, const float* __restrict__ f0i_g,
    float* __restrict__ out)
{
    const int b = blockIdx.x;
    const int lane = threadIdx.x;
    const int half = lane >> 5;
    const int tap  = lane & 31;
    const bool lo  = (half == 0);

    const int wbase = b * 128 + half * 64 + tap;
    float wAr = w0r_g[wbase],      wAi = w0i_g[wbase];
    float wBr = w0r_g[wbase + 32], wBi = w0i_g[wbase + 32];

    float fr = f0r_g[b * 2 + half];
    float fi = f0i_g[b * 2 + half];
    const float invf0 = frsq(fmaf(fr, fr, fi * fi));
    float psr = fr * invf0, psm = -fi * invf0;

    const float2* __restrict__ ur2 = (const float2*)u_r + (size_t)b * kL * 32;
    const float2* __restrict__ ui2 = (const float2*)u_i + (size_t)b * kL * 32;
    const float2* __restrict__ xr2 = (const float2*)x_r + (size_t)b * kL;
    const float2* __restrict__ xi2 = (const float2*)x_i + (size_t)b * kL;
    float2* __restrict__ ob2 = (float2*)out + (size_t)b * kL * 2;

    float2 Au[kPF], Aq[kPF], AxR[kPF], AxI[kPF];
    float2 Bu[kPF], Bq[kPF], BxR[kPF], BxI[kPF];
    float suA[kPF], suB[kPF];
    float kR[kPF], kI[kPF];
    float sdpr = 0.0f, sdpi = 0.0f;

    auto loadChunk = [&](float2 (&u)[kPF], float2 (&q)[kPF],
                         float2 (&xR)[kPF], float2 (&xI)[kPF], int chunk) {
#pragma unroll
        for (int s = 0; s < kPF; ++s) {
            int t = chunk * kPF + s;
            t = t < kL ? t : kL - 1;
            u[s]  = ur2[(size_t)t * 32 + tap];
            q[s]  = ui2[(size_t)t * 32 + tap];
            xR[s] = xr2[t];
            xI[s] = xi2[t];
        }
        __builtin_amdgcn_sched_barrier(0);
    };

    auto calcSu = [&](float2 (&u)[kPF], float2 (&q)[kPF], float (&su)[kPF]) {
        float e[kPF];
#pragma unroll
        for (int s = 0; s < kPF; ++s) {
            float t0 = u[s].x * u[s].x;
            t0 = fmaf(u[s].y, u[s].y, t0);
            t0 = fmaf(q[s].x, q[s].x, t0);
            t0 = fmaf(q[s].y, q[s].y, t0);
            e[s] = t0;
        }
#pragma unroll
        for (int s = 0; s < kPF; ++s) { DPP_ADD_F32(e[s], 0x111); }
#pragma unroll
        for (int s = 0; s < kPF; ++s) { DPP_ADD_F32(e[s], 0x112); }
#pragma unroll
        for (int s = 0; s < kPF; ++s) { DPP_ADD_F32(e[s], 0x114); }
#pragma unroll
        for (int s = 0; s < kPF; ++s) { DPP_ADD_F32(e[s], 0x118); }
#pragma unroll
        for (int s = 0; s < kPF; ++s) { DPP_ADD_F32(e[s], 0x142); }
#pragma unroll
        for (int s = 0; s < kPF; ++s) su[s] = kLrW * frcp(rl(e[s], 31) + kEps);
    };

    auto body = [&](int s, float2 (&u)[kPF], float2 (&q)[kPF],
                    float2 (&xR)[kPF], float2 (&xI)[kPF], float (&su)[kPF],
                    bool first) {
        const float2 uc = u[s], qc = q[s];
        if (first) {
            const float dr0 = lo ? xR[0].x : xR[0].y;
            const float di0 = lo ? xI[0].x : xI[0].y;
            sdpr = su[0] * fmaf(dr0, psr, -di0 * psm);
            sdpi = su[0] * fmaf(dr0, psm,  di0 * psr);
        }
        float pr = wAr * uc.x;
        pr = fmaf(-wAi, qc.x, pr); pr = fmaf(wBr, uc.y, pr); pr = fmaf(-wBi, qc.y, pr);
        float pi = wAr * qc.x;
        pi = fmaf(wAi, uc.x, pi); pi = fmaf(wBr, qc.y, pi); pi = fmaf(wBi, uc.y, pi);
        DPP_ADD_F32(pr, 0x111); DPP_ADD_F32(pi, 0x111);
        DPP_ADD_F32(pr, 0x112); DPP_ADD_F32(pi, 0x112);
        DPP_ADD_F32(pr, 0x114); DPP_ADD_F32(pi, 0x114);
        DPP_ADD_F32(pr, 0x118); DPP_ADD_F32(pi, 0x118);
        DPP_ADD_F32(pr, 0x142); DPP_ADD_F32(pi, 0x142);
        const float v0r = rl(pr, 31), v1r = rl(pr, 63);
        const float v0i = rl(pi, 31), v1i = rl(pi, 63);
        const float vr = lo ? v0r : v1r;
        const float vi = lo ? v0i : v1i;

        const float sun = su[s];
        const float tr = fmaf(-sun, vr, sdpr);
        const float ti = fmaf(-sun, vi, sdpi);
        wAr = fmaf(tr, uc.x, fmaf(ti, qc.x, wAr));
        wAi = fmaf(ti, uc.x, fmaf(-tr, qc.x, wAi));
        wBr = fmaf(tr, uc.y, fmaf(ti, qc.y, wBr));
        wBi = fmaf(ti, uc.y, fmaf(-tr, qc.y, wBi));

        const float dr = lo ? xR[s].x : xR[s].y;
        const float di = lo ? xI[s].x : xI[s].y;
        const float kr = fmaf(vr, fr, -vi * fi);
        const float ki = fmaf(vr, fi,  vi * fr);
        kR[s] = kr; kI[s] = ki;
        const float efr = dr - kr, efi = di - ki;
        float ven = v0r * v0r;
        ven = fmaf(v0i, v0i, ven);
        ven = fmaf(v1r, v1r, ven);
        ven = fmaf(v1i, v1i, ven);
        const float nv = frcp(ven + kEps);
        float hr = efr * vr; hr = fmaf(efi, vi, hr);
        float hi = efi * vr; hi = fmaf(-efr, vi, hi);
        hr *= nv; hi *= nv;
        float mg = hr * hr; mg = fmaf(hi, hi, mg);
        const float sc = fminf(1.0f, kGradMax * frsq(mg));
        const float scl = kLrF * sc;
        fr = fmaf(scl, hr, fr);
        fi = fmaf(scl, hi, fi);
        const float invf = frsq(fmaf(fr, fr, fi * fi));
        psr = fr * invf; psm = -fi * invf;
        if (s + 1 < kPF) {
            const float dnr = lo ? xR[s + 1].x : xR[s + 1].y;
            const float dni = lo ? xI[s + 1].x : xI[s + 1].y;
            sdpr = su[s + 1] * fmaf(dnr, psr, -dni * psm);
            sdpi = su[s + 1] * fmaf(dnr, psm,  dni * psr);
        }
    };

    auto processChunk = [&](int tbase, float2 (&u)[kPF], float2 (&q)[kPF],
                            float2 (&xR)[kPF], float2 (&xI)[kPF], float (&su)[kPF]) {
#pragma unroll
        for (int s = 0; s < kPF; ++s)
            body(s, u, q, xR, xI, su, s == 0);
        if (tap == 0) {
#pragma unroll
            for (int s = 0; s < kPF; ++s)
                ob2[(size_t)(tbase + s) * 2 + half] = make_float2(kR[s], kI[s]);
        }
    };

    loadChunk(Au, Aq, AxR, AxI, 0);
    loadChunk(Bu, Bq, BxR, BxI, 1);
    calcSu(Au, Aq, suA);

    for (int c = 0; c < kNC; c += 2) {
        processChunk(c * kPF, Au, Aq, AxR, AxI, suA);
        loadChunk(Au, Aq, AxR, AxI, (c + 2 < kNC) ? c + 2 : kNC - 1);
        calcSu(Bu, Bq, suB);
        processChunk((c + 1) * kPF, Bu, Bq, BxR, BxI, suB);
        loadChunk(Bu, Bq, BxR, BxI, (c + 3 < kNC) ? c + 3 : kNC - 1);
        calcSu(Au, Aq, suA);
    }
}

} // namespace

extern "C" void kernel_launch(void* const* d_in, const int* in_sizes, int n_in,
                              void* d_out, int out_size, void* d_ws, size_t ws_size,
                              hipStream_t stream) {
    const float* u_r  = (const float*)d_in[0];
    const float* u_i  = (const float*)d_in[1];
    const float* x_r  = (const float*)d_in[2];
    const float* x_i  = (const float*)d_in[3];
    const float* w0_r = (const float*)d_in[4];
    const float* w0_i = (const float*)d_in[5];
    const float* f0_r = (const float*)d_in[6];
    const float* f0_i = (const float*)d_in[7];
    float* out = (float*)d_out;

    const size_t need = (size_t)kB * kL * 8 * sizeof(float);   // 8 MB meta
    if (ws_size >= need) {
        float* meta = (float*)d_ws;
        pre_kernel<<<dim3(kB * kL / 4), dim3(256), 0, stream>>>(u_r, u_i, x_r, x_i, meta);
        adf_kernel<<<dim3(kB), dim3(64), 0, stream>>>(
            u_r, u_i, w0_r, w0_i, f0_r, f0_i, meta, out);
    } else {
        adf_fb<<<dim3(kB), dim3(64), 0, stream>>>(
            u_r, u_i, x_r, x_i, w0_r, w0_i, f0_r, f0_i, out);
    }
}

// Round 17
// 703.830 us; speedup vs baseline: 1.0478x; 1.0232x over previous
//
#include <hip/hip_runtime.h>

namespace {

constexpr int kB = 64;
constexpr int kL = 4096;
constexpr float kLrW = 1.0f / 64.0f;
constexpr float kLrF = 1.0f / 128.0f;
constexpr float kGradMax = 30.0f;
constexpr float kEps = 1e-9f;
constexpr int kPF = 8;
constexpr int kNC = kL / kPF;

#define DPP_ADD_F32(v, ctrl)                                                   \
    v += __int_as_float(__builtin_amdgcn_update_dpp(                           \
        0, __float_as_int(v), (ctrl), 0xF, 0xF, true))

__device__ __forceinline__ float rl(float v, int l) {
    return __int_as_float(__builtin_amdgcn_readlane(__float_as_int(v), l));
}
__device__ __forceinline__ float frcp(float x) { return __builtin_amdgcn_rcpf(x); }
__device__ __forceinline__ float frsq(float x) { return __builtin_amdgcn_rsqf(x); }

// ---------------- packed-f32 complex primitives (VOP3P, r13-proven) --------
__device__ __forceinline__ void cfma(float2& a, const float2 s, const float2 u) {
    asm("v_pk_fma_f32 %0, %1, %2, %0 op_sel:[1,1,0] op_sel_hi:[1,0,1] neg_lo:[0,1,0]\n\t"
        "v_pk_fma_f32 %0, %1, %2, %0 op_sel:[0,0,0] op_sel_hi:[0,1,1]"
        : "+v"(a) : "v"(s), "v"(u));
}
__device__ __forceinline__ void cfma_conj(float2& a, const float2 s, const float2 u) {
    asm("v_pk_fma_f32 %0, %1, %2, %0 op_sel:[1,1,0] op_sel_hi:[1,0,1]\n\t"
        "v_pk_fma_f32 %0, %1, %2, %0 op_sel:[0,0,0] op_sel_hi:[0,1,1] neg_hi:[0,1,0]"
        : "+v"(a) : "v"(s), "v"(u));
}
__device__ __forceinline__ float2 cmul(const float2 s, const float2 u) {
    float2 r;
    asm("v_pk_mul_f32 %0, %1, %2 op_sel:[1,1] op_sel_hi:[1,0] neg_lo:[0,1]\n\t"
        "v_pk_fma_f32 %0, %1, %2, %0 op_sel:[0,0,0] op_sel_hi:[0,1,1]"
        : "=&v"(r) : "v"(s), "v"(u));
    return r;
}
__device__ __forceinline__ float2 cmul_conj(const float2 s, const float2 u) {
    float2 r;
    asm("v_pk_mul_f32 %0, %1, %2 op_sel:[1,1] op_sel_hi:[1,0]\n\t"
        "v_pk_fma_f32 %0, %1, %2, %0 op_sel:[0,0,0] op_sel_hi:[0,1,1] neg_hi:[0,1,0]"
        : "=&v"(r) : "v"(s), "v"(u));
    return r;
}
__device__ __forceinline__ float2 pk_fnma(const float2 s, const float2 u, const float2 c) {
    float2 r;
    asm("v_pk_fma_f32 %0, %1, %2, %3 neg_lo:[1,0,0] neg_hi:[1,0,0]"
        : "=v"(r) : "v"(s), "v"(u), "v"(c));
    return r;
}
__device__ __forceinline__ float2 pk_sub(const float2 a, const float2 b) {
    float2 r;
    asm("v_pk_add_f32 %0, %1, %2 neg_lo:[0,1] neg_hi:[0,1]" : "=v"(r) : "v"(a), "v"(b));
    return r;
}
__device__ __forceinline__ float2 pk_mul(const float2 a, const float2 b) {
    float2 r;
    asm("v_pk_mul_f32 %0, %1, %2" : "=v"(r) : "v"(a), "v"(b));
    return r;
}

typedef unsigned u32x2v __attribute__((ext_vector_type(2)));
__device__ __forceinline__ float pairsum16(float v) {
    u32x2v r = __builtin_amdgcn_permlane16_swap(__float_as_uint(v),
                                                __float_as_uint(v), false, false);
    return __uint_as_float(r[0]) + __uint_as_float(r[1]);
}
__device__ __forceinline__ float pairsum32(float v) {
    u32x2v r = __builtin_amdgcn_permlane32_swap(__float_as_uint(v),
                                                __float_as_uint(v), false, false);
    return __uint_as_float(r[0]) + __uint_as_float(r[1]);
}
__device__ __forceinline__ float rowsum16(float v) {
    DPP_ADD_F32(v, 0x121); DPP_ADD_F32(v, 0x122);
    DPP_ADD_F32(v, 0x124); DPP_ADD_F32(v, 0x128);
    return v;
}

// ---------- pre-kernel (r10/r13-proven): meta[b,t][8]={su,su,d0r,d0i,d1r,d1i,0,0}
__global__ __launch_bounds__(256, 1) void pre_kernel(
    const float* __restrict__ u_r, const float* __restrict__ u_i,
    const float* __restrict__ x_r, const float* __restrict__ x_i,
    float* __restrict__ meta)
{
    const int lane = threadIdx.x & 63;
    const int idx = blockIdx.x * 4 + (threadIdx.x >> 6);   // flat b*L + t
    const float a = u_r[(size_t)idx * 64 + lane];
    const float c = u_i[(size_t)idx * 64 + lane];
    float e = fmaf(a, a, c * c);
    e = rowsum16(e);
    e = pairsum16(e);
    e = pairsum32(e);
    if (lane == 0) {
        const float su = kLrW * frcp(e + kEps);
        const float2 xr = *(const float2*)(x_r + (size_t)idx * 2);
        const float2 xi = *(const float2*)(x_i + (size_t)idx * 2);
        float4* m = (float4*)(meta + (size_t)idx * 8);
        m[0] = make_float4(su, su, xr.x, xi.x);
        m[1] = make_float4(xr.y, xi.y, 0.0f, 0.0f);
    }
}

// ---------- main scan kernel: r13 skeleton, ROTATED pipeline ----------------
// prC/piC carry the reduced (not yet broadcast) chains for v(t), produced in
// body t-1. The DPP chain of step t+1 is textually woven with step t's f-path
// so its latency settles before body t+1's readlane.
__global__ __launch_bounds__(64, 1) void adf_kernel(
    const float* __restrict__ u_r, const float* __restrict__ u_i,
    const float* __restrict__ w0r_g, const float* __restrict__ w0i_g,
    const float* __restrict__ f0r_g, const float* __restrict__ f0i_g,
    const float* __restrict__ meta, float* __restrict__ out)
{
    const int b = blockIdx.x;
    const int lane = threadIdx.x;
    const int half = lane >> 5;
    const int tap  = lane & 31;

    const int wbase = b * 128 + half * 64 + tap;
    float2 wA = make_float2(w0r_g[wbase],      w0i_g[wbase]);
    float2 wB = make_float2(w0r_g[wbase + 32], w0i_g[wbase + 32]);

    float2 f2 = make_float2(f0r_g[b * 2 + half], f0i_g[b * 2 + half]);
    float invf = frsq(fmaf(f2.x, f2.x, f2.y * f2.y));   // carried: 1/|f|

    const float2* __restrict__ ur2 = (const float2*)u_r + (size_t)b * kL * 32;
    const float2* __restrict__ ui2 = (const float2*)u_i + (size_t)b * kL * 32;
    const float* __restrict__ mp = meta + (size_t)b * kL * 8;
    float2* __restrict__ ob2 = (float2*)out + (size_t)b * kL * 2;

    float2 Au[kPF], Aq[kPF], Asu[kPF], Ad[kPF];
    float2 Bu[kPF], Bq[kPF], Bsu[kPF], Bd[kPF];
    float2 kO[kPF];
    float2 sdp2 = make_float2(0.f, 0.f);
    float prC = 0.f, piC = 0.f;      // reduced partial chains for current t

    auto loadChunk = [&](float2 (&u)[kPF], float2 (&q)[kPF],
                         float2 (&su)[kPF], float2 (&d)[kPF], int chunk) {
#pragma unroll
        for (int s = 0; s < kPF; ++s) {
            int t = chunk * kPF + s;
            t = t < kL ? t : kL - 1;
            u[s]  = ur2[(size_t)t * 32 + tap];
            q[s]  = ui2[(size_t)t * 32 + tap];
            su[s] = *(const float2*)(mp + (size_t)t * 8);                  // (su,su)
            d[s]  = *(const float2*)(mp + (size_t)t * 8 + 2 + 2 * half);   // (dr,di)
        }
        __builtin_amdgcn_sched_barrier(0);   // keep prefetch ahead of compute (r7)
    };

    // sdp = (su*invf) * (d*conj(f)) -- psi-free (r16)
    auto mk_sdp = [&](const float2 su, const float2 d) {
        const float2 P = cmul_conj(d, f2);
        const float g = su.x * invf;
        return pk_mul(make_float2(g, g), P);
    };

    // One rotated body for step t:
    //  cA/cB = u(t); nA/nB = u(t+1); sun/dn = meta(t+1)
    auto body = [&](int s, const float2 cA, const float2 cB,
                    const float2 nA, const float2 nB,
                    const float2 suc, const float2 dc,
                    const float2 sun, const float2 dn) {
        // broadcast v(t) (chains settled during previous body's f-path)
        const float v0r = rl(prC, 31), v1r = rl(prC, 63);
        const float v0i = rl(piC, 31), v1i = rl(piC, 63);
        const float2 v2 = make_float2(half ? v1r : v0r, half ? v1i : v0i);

        // tau = sdp - su*v ; w += tau*conj(u)
        const float2 tau = pk_fnma(suc, v2, sdp2);
        cfma_conj(wA, tau, cA);
        cfma_conj(wB, tau, cB);

        // partials for v(t+1) with updated w
        float2 p = cmul(wA, nA);
        cfma(p, wB, nB);
        float pr = p.x, pi = p.y;

        // DPP chain for t+1 woven with step-t f-path
        DPP_ADD_F32(pr, 0x111); DPP_ADD_F32(pi, 0x111);
        const float2 k2 = cmul(v2, f2);            // k = v*f
        kO[s] = k2;
        DPP_ADD_F32(pr, 0x112); DPP_ADD_F32(pi, 0x112);
        const float2 ef = pk_sub(dc, k2);          // e_f = d - k
        DPP_ADD_F32(pr, 0x114); DPP_ADD_F32(pi, 0x114);
        float ven = v0r * v0r;
        ven = fmaf(v0i, v0i, ven);
        ven = fmaf(v1r, v1r, ven);
        ven = fmaf(v1i, v1i, ven);
        DPP_ADD_F32(pr, 0x118); DPP_ADD_F32(pi, 0x118);
        const float nv = frcp(ven + kEps);
        const float2 H = cmul_conj(ef, v2);        // ef*conj(v)
        DPP_ADD_F32(pr, 0x142); DPP_ADD_F32(pi, 0x142);
        prC = pr; piC = pi;

        // f-path tail (DPP settles underneath)
        const float MH = fmaf(H.x, H.x, H.y * H.y);
        const float sc = fminf(nv, kGradMax * frsq(MH));   // norm+clip folded
        const float scl = kLrF * sc;
        f2.x = fmaf(scl, H.x, f2.x);               // f -= lrF*gf
        f2.y = fmaf(scl, H.y, f2.y);
        invf = frsq(fmaf(f2.x, f2.x, f2.y * f2.y));
        sdp2 = mk_sdp(sun, dn);                    // sdp(t+1)
    };

    auto processChunk = [&](int tbase, float2 (&u)[kPF], float2 (&q)[kPF],
                            float2 (&su)[kPF], float2 (&d)[kPF],
                            const float2 nu0, const float2 nq0,
                            const float2 su0n, const float2 d0n) {
#pragma unroll
        for (int s = 0; s < kPF; ++s) {
            const float2 cA = make_float2(u[s].x, q[s].x);
            const float2 cB = make_float2(u[s].y, q[s].y);
            float2 nA, nB, sun, dn;
            if (s + 1 < kPF) {
                nA = make_float2(u[s + 1].x, q[s + 1].x);
                nB = make_float2(u[s + 1].y, q[s + 1].y);
                sun = su[s + 1]; dn = d[s + 1];
            } else {
                nA = nu0; nB = nq0; sun = su0n; dn = d0n;
            }
            body(s, cA, cB, nA, nB, su[s], d[s], sun, dn);
        }
        if (tap == 0) {
#pragma unroll
            for (int s = 0; s < kPF; ++s)
                ob2[(size_t)(tbase + s) * 2 + half] = kO[s];
        }
    };

    loadChunk(Au, Aq, Asu, Ad, 0);
    loadChunk(Bu, Bq, Bsu, Bd, 1);

    // prologue: chains + sdp for t=0
    {
        const float2 cA = make_float2(Au[0].x, Aq[0].x);
        const float2 cB = make_float2(Au[0].y, Aq[0].y);
        float2 p = cmul(wA, cA);
        cfma(p, wB, cB);
        float pr = p.x, pi = p.y;
        DPP_ADD_F32(pr, 0x111); DPP_ADD_F32(pi, 0x111);
        DPP_ADD_F32(pr, 0x112); DPP_ADD_F32(pi, 0x112);
        DPP_ADD_F32(pr, 0x114); DPP_ADD_F32(pi, 0x114);
        DPP_ADD_F32(pr, 0x118); DPP_ADD_F32(pi, 0x118);
        DPP_ADD_F32(pr, 0x142); DPP_ADD_F32(pi, 0x142);
        prC = pr; piC = pi;
        sdp2 = mk_sdp(Asu[0], Ad[0]);
    }

    for (int c = 0; c < kNC; c += 2) {
        processChunk(c * kPF, Au, Aq, Asu, Ad,
                     make_float2(Bu[0].x, Bq[0].x), make_float2(Bu[0].y, Bq[0].y),
                     Bsu[0], Bd[0]);
        loadChunk(Au, Aq, Asu, Ad, (c + 2 < kNC) ? c + 2 : kNC - 1);
        processChunk((c + 1) * kPF, Bu, Bq, Bsu, Bd,
                     make_float2(Au[0].x, Aq[0].x), make_float2(Au[0].y, Aq[0].y),
                     Asu[0], Ad[0]);
        loadChunk(Bu, Bq, Bsu, Bd, (c + 3 < kNC) ? c + 3 : kNC - 1);
    }
}

// ---------- fallback (r7, 838 us, proven) if ws too small -------------------
__global__ __launch_bounds__(64, 1) void adf_fb(
    const float* __restrict__ u_r, const float* __restrict__ u_i,
    const float* __restrict__ x_r, const float* __restrict__ x_i,
    const float* __restrict__ w0r_g, const float* __restrict__ w0i_g,
    const float* __restrict__ f0r_g, const float* __restrict__ f0i_g,
    float* __restrict__ out)
{
    const int b = blockIdx.x;
    const int lane = threadIdx.x;
    const int half = lane >> 5;
    const int tap  = lane & 31;
    const bool lo  = (half == 0);

    const int wbase = b * 128 + half * 64 + tap;
    float wAr = w0r_g[wbase],      wAi = w0i_g[wbase];
    float wBr = w0r_g[wbase + 32], wBi = w0i_g[wbase + 32];

    float fr = f0r_g[b * 2 + half];
    float fi = f0i_g[b * 2 + half];
    const float invf0 = frsq(fmaf(fr, fr, fi * fi));
    float psr = fr * invf0, psm = -fi * invf0;

    const float2* __restrict__ ur2 = (const float2*)u_r + (size_t)b * kL * 32;
    const float2* __restrict__ ui2 = (const float2*)u_i + (size_t)b * kL * 32;
    const float2* __restrict__ xr2 = (const float2*)x_r + (size_t)b * kL;
    const float2* __restrict__ xi2 = (const float2*)x_i + (size_t)b * kL;
    float2* __restrict__ ob2 = (float2*)out + (size_t)b * kL * 2;

    float2 Au[kPF], Aq[kPF], AxR[kPF], AxI[kPF];
    float2 Bu[kPF], Bq[kPF], BxR[kPF], BxI[kPF];
    float suA[kPF], suB[kPF];
    float kR[kPF], kI[kPF];
    float sdpr = 0.0f, sdpi = 0.0f;

    auto loadChunk = [&](float2 (&u)[kPF], float2 (&q)[kPF],
                         float2 (&xR)[kPF], float2 (&xI)[kPF], int chunk) {
#pragma unroll
        for (int s = 0; s < kPF; ++s) {
            int t = chunk * kPF + s;
            t = t < kL ? t : kL - 1;
            u[s]  = ur2[(size_t)t * 32 + tap];
            q[s]  = ui2[(size_t)t * 32 + tap];
            xR[s] = xr2[t];
            xI[s] = xi2[t];
        }
        __builtin_amdgcn_sched_barrier(0);
    };

    auto calcSu = [&](float2 (&u)[kPF], float2 (&q)[kPF], float (&su)[kPF]) {
        float e[kPF];
#pragma unroll
        for (int s = 0; s < kPF; ++s) {
            float t0 = u[s].x * u[s].x;
            t0 = fmaf(u[s].y, u[s].y, t0);
            t0 = fmaf(q[s].x, q[s].x, t0);
            t0 = fmaf(q[s].y, q[s].y, t0);
            e[s] = t0;
        }
#pragma unroll
        for (int s = 0; s < kPF; ++s) { DPP_ADD_F32(e[s], 0x111); }
#pragma unroll
        for (int s = 0; s < kPF; ++s) { DPP_ADD_F32(e[s], 0x112); }
#pragma unroll
        for (int s = 0; s < kPF; ++s) { DPP_ADD_F32(e[s], 0x114); }
#pragma unroll
        for (int s = 0; s < kPF; ++s) { DPP_ADD_F32(e[s], 0x118); }
#pragma unroll
        for (int s = 0; s < kPF; ++s) { DPP_ADD_F32(e[s], 0x142); }
#pragma unroll
        for (int s = 0; s < kPF; ++s) su[s] = kLrW * frcp(rl(e[s], 31) + kEps);
    };

    auto body = [&](int s, float2 (&u)[kPF], float2 (&q)[kPF],
                    float2 (&xR)[kPF], float2 (&xI)[kPF], float (&su)[kPF],
                    bool first) {
        const float2 uc = u[s], qc = q[s];
        if (first) {
            const float dr0 = lo ? xR[0].x : xR[0].y;
            const float di0 = lo ? xI[0].x : xI[0].y;
            sdpr = su[0] * fmaf(dr0, psr, -di0 * psm);
            sdpi = su[0] * fmaf(dr0, psm,  di0 * psr);
        }
        float pr = wAr * uc.x;
        pr = fmaf(-wAi, qc.x, pr); pr = fmaf(wBr, uc.y, pr); pr = fmaf(-wBi, qc.y, pr);
        float pi = wAr * qc.x;
        pi = fmaf(wAi, uc.x, pi); pi = fmaf(wBr, qc.y, pi); pi = fmaf(wBi, uc.y, pi);
        DPP_ADD_F32(pr, 0x111); DPP_ADD_F32(pi, 0x111);
        DPP_ADD_F32(pr, 0x112); DPP_ADD_F32(pi, 0x112);
        DPP_ADD_F32(pr, 0x114); DPP_ADD_F32(pi, 0x114);
        DPP_ADD_F32(pr, 0x118); DPP_ADD_F32(pi, 0x118);
        DPP_ADD_F32(pr, 0x142); DPP_ADD_F32(pi, 0x142);
        const float v0r = rl(pr, 31), v1r = rl(pr, 63);
        const float v0i = rl(pi, 31), v1i = rl(pi, 63);
        const float vr = lo ? v0r : v1r;
        const float vi = lo ? v0i : v1i;

        const float sun = su[s];
        const float tr = fmaf(-sun, vr, sdpr);
        const float ti = fmaf(-sun, vi, sdpi);
        wAr = fmaf(tr, uc.x, fmaf(ti, qc.x, wAr));
        wAi = fmaf(ti, uc.x, fmaf(-tr, qc.x, wAi));
        wBr = fmaf(tr, uc.y, fmaf(ti, qc.y, wBr));
        wBi = fmaf(ti, uc.y, fmaf(-tr, qc.y, wBi));

        const float dr = lo ? xR[s].x : xR[s].y;
        const float di = lo ? xI[s].x : xI[s].y;
        const float kr = fmaf(vr, fr, -vi * fi);
        const float ki = fmaf(vr, fi,  vi * fr);
        kR[s] = kr; kI[s] = ki;
        const float efr = dr - kr, efi = di - ki;
        float ven = v0r * v0r;
        ven = fmaf(v0i, v0i, ven);
        ven = fmaf(v1r, v1r, ven);
        ven = fmaf(v1i, v1i, ven);
        const float nv = frcp(ven + kEps);
        float hr = efr * vr; hr = fmaf(efi, vi, hr);
        float hi = efi * vr; hi = fmaf(-efr, vi, hi);
        hr *= nv; hi *= nv;
        float mg = hr * hr; mg = fmaf(hi, hi, mg);
        const float sc = fminf(1.0f, kGradMax * frsq(mg));
        const float scl = kLrF * sc;
        fr = fmaf(scl, hr, fr);
        fi = fmaf(scl, hi, fi);
        const float invf = frsq(fmaf(fr, fr, fi * fi));
        psr = fr * invf; psm = -fi * invf;
        if (s + 1 < kPF) {
            const float dnr = lo ? xR[s + 1].x : xR[s + 1].y;
            const float dni = lo ? xI[s + 1].x : xI[s + 1].y;
            sdpr = su[s + 1] * fmaf(dnr, psr, -dni * psm);
            sdpi = su[s + 1] * fmaf(dnr, psm,  dni * psr);
        }
    };

    auto processChunk = [&](int tbase, float2 (&u)[kPF], float2 (&q)[kPF],
                            float2 (&xR)[kPF], float2 (&xI)[kPF], float (&su)[kPF]) {
#pragma unroll
        for (int s = 0; s < kPF; ++s)
            body(s, u, q, xR, xI, su, s == 0);
        if (tap == 0) {
#pragma unroll
            for (int s = 0; s < kPF; ++s)
                ob2[(size_t)(tbase + s) * 2 + half] = make_float2(kR[s], kI[s]);
        }
    };

    loadChunk(Au, Aq, AxR, AxI, 0);
    loadChunk(Bu, Bq, BxR, BxI, 1);
    calcSu(Au, Aq, suA);

    for (int c = 0; c < kNC; c += 2) {
        processChunk(c * kPF, Au, Aq, AxR, AxI, suA);
        loadChunk(Au, Aq, AxR, AxI, (c + 2 < kNC) ? c + 2 : kNC - 1);
        calcSu(Bu, Bq, suB);
        processChunk((c + 1) * kPF, Bu, Bq, BxR, BxI, suB);
        loadChunk(Bu, Bq, BxR, BxI, (c + 3 < kNC) ? c + 3 : kNC - 1);
        calcSu(Au, Aq, suA);
    }
}

} // namespace

extern "C" void kernel_launch(void* const* d_in, const int* in_sizes, int n_in,
                              void* d_out, int out_size, void* d_ws, size_t ws_size,
                              hipStream_t stream) {
    const float* u_r  = (const float*)d_in[0];
    const float* u_i  = (const float*)d_in[1];
    const float* x_r  = (const float*)d_in[2];
    const float* x_i  = (const float*)d_in[3];
    const float* w0_r = (const float*)d_in[4];
    const float* w0_i = (const float*)d_in[5];
    const float* f0_r = (const float*)d_in[6];
    const float* f0_i = (const float*)d_in[7];
    float* out = (float*)d_out;

    const size_t need = (size_t)kB * kL * 8 * sizeof(float);   // 8 MB meta
    if (ws_size >= need) {
        float* meta = (float*)d_ws;
        pre_kernel<<<dim3(kB * kL / 4), dim3(256), 0, stream>>>(u_r, u_i, x_r, x_i, meta);
        adf_kernel<<<dim3(kB), dim3(64), 0, stream>>>(
            u_r, u_i, w0_r, w0_i, f0_r, f0_i, meta, out);
    } else {
        adf_fb<<<dim3(kB), dim3(64), 0, stream>>>(
            u_r, u_i, x_r, x_i, w0_r, w0_i, f0_r, f0_i, out);
    }
}